// Round 6
// baseline (393.802 us; speedup 1.0000x reference)
//
#include <hip/hip_runtime.h>
#include <cstdint>

#define NN 4
#define CC 64
#define VV 25
#define TT 300
#define MM 2
#define HH 8
#define HD 32
#define EE 256

typedef short bf16x8 __attribute__((ext_vector_type(8)));
typedef float f32x4 __attribute__((ext_vector_type(4)));

__device__ __forceinline__ unsigned short f2bf(float f) {
  union { float f; unsigned u; } x; x.f = f;
  unsigned r = x.u + 0x7FFF + ((x.u >> 16) & 1);  // RNE
  return (unsigned short)(r >> 16);
}
__device__ __forceinline__ float bf2f(unsigned short s) {
  union { unsigned u; float f; } x; x.u = ((unsigned)s) << 16;
  return x.f;
}
__device__ __forceinline__ float bperm(int byteaddr, float v) {
  return __int_as_float(__builtin_amdgcn_ds_bpermute(byteaddr, __float_as_int(v)));
}

// ws layout (unsigned short units):
//   Qh,Ql,Kh,Kl : [b,v,h,t<300,d] (15,360,000 each) [Q xlog2e, K x1/16]
//   Vt : [b,v,h,d][t pad 320] (16,384,000)
//   Oh,Ol : [b,v,t<300,e] (15,360,000 each)
//   WhT,WlT [c][e] (16,384 each); WqTh,WqTl [e][c] (49,152 each);
//   btPad [704][32] bf16, rows 20..618 = bias_table, else 0 (22,528)
#define QKN 15360000
#define VTN 16384000
#define LOG2E 1.4426950408889634f

// ---------------- prep: transpose/split weights + bf16 bias table ----------------
__global__ __launch_bounds__(256) void prep_kernel(
    const float* __restrict__ w_qkv, const float* __restrict__ w_merge,
    const float* __restrict__ bias_table,
    unsigned short* __restrict__ WqTh, unsigned short* __restrict__ WqTl,
    unsigned short* __restrict__ WhT, unsigned short* __restrict__ WlT,
    unsigned short* __restrict__ btPad)
{
  int i = blockIdx.x * 256 + threadIdx.x;
  if (i < 49152) {                      // w_qkv [c][768] -> [e][c] hi/lo
    int c = i / 768, e = i % 768;
    float v = w_qkv[i];
    unsigned short hb = f2bf(v);
    WqTh[e * 64 + c] = hb; WqTl[e * 64 + c] = f2bf(v - bf2f(hb));
  } else if (i < 65536) {               // w_merge [e][64] -> [c][e] hi/lo
    int j = i - 49152;
    int e = j >> 6, c = j & 63;
    float v = w_merge[j];
    unsigned short hb = f2bf(v);
    WhT[c * EE + e] = hb; WlT[c * EE + e] = f2bf(v - bf2f(hb));
  } else if (i < 65536 + 22528) {       // bias_table -> padded bf16 [704][32]
    int j = i - 65536;
    int row = j >> 5, d = j & 31;
    int g = row - 20;
    float v = (g >= 0 && g < 2 * TT - 1) ? bias_table[g * 32 + d] : 0.f;
    btPad[j] = f2bf(v);
  }
}

// ---------------- Kernel A: QKV projection via MFMA (unchanged, known-good) ----------------
__global__ __launch_bounds__(256, 3) void qkv_kernel(
    const float* __restrict__ x, const float* __restrict__ b_qkv,
    const unsigned short* __restrict__ WqTh, const unsigned short* __restrict__ WqTl,
    unsigned short* __restrict__ Qh, unsigned short* __restrict__ Ql,
    unsigned short* __restrict__ Kh, unsigned short* __restrict__ Kl,
    unsigned short* __restrict__ Vt)
{
  __shared__ union {
    float a[64 * 69];             // sA[c][t], stride 69
    unsigned short vtr[256 * 66]; // V transpose buffer [e'][t]
  } sm;

  int blk = blockIdx.x;
  int tt = blk % 5; blk /= 5;
  int v25 = blk % 25; int b = blk / 25;
  int n = b >> 1, m = b & 1;
  int t0 = tt * 60;
  int tid = threadIdx.x;
  int w = tid >> 6, lane = tid & 63, quad = lane >> 4, c16 = lane & 15;

  for (int i = tid; i < 64 * 64; i += 256) {
    int c = i >> 6, t = i & 63;
    float val = 0.f;
    if (t < 60) val = x[((((size_t)n * CC + c) * VV + v25) * TT + (t0 + t)) * MM + m];
    sm.a[c * 69 + t] = val;
  }
  __syncthreads();

  bf16x8 ah[4][2], al[4][2];
  #pragma unroll
  for (int mt = 0; mt < 4; ++mt)
    #pragma unroll
    for (int kc = 0; kc < 2; ++kc)
      #pragma unroll
      for (int j = 0; j < 8; ++j) {
        float f = sm.a[(kc * 32 + quad * 8 + j) * 69 + mt * 16 + c16];
        unsigned short hb = f2bf(f);
        ah[mt][kc][j] = (short)hb;
        al[mt][kc][j] = (short)f2bf(f - bf2f(hb));
      }
  __syncthreads();  // sA dead; sVt (union) may be written

  size_t bv = (size_t)(b * VV + v25);
  int e0 = w * 192;
  for (int nt = 0; nt < 12; ++nt) {
    int ebase = e0 + nt * 16;
    int e = ebase + c16;
    bf16x8 bh[2], bl[2];
    #pragma unroll
    for (int kc = 0; kc < 2; ++kc) {
      bh[kc] = *(const bf16x8*)&WqTh[(size_t)e * 64 + kc * 32 + quad * 8];
      bl[kc] = *(const bf16x8*)&WqTl[(size_t)e * 64 + kc * 32 + quad * 8];
    }
    f32x4 acc[4];
    #pragma unroll
    for (int mt = 0; mt < 4; ++mt) {
      acc[mt] = (f32x4){0.f, 0.f, 0.f, 0.f};
      #pragma unroll
      for (int kc = 0; kc < 2; ++kc) {
        acc[mt] = __builtin_amdgcn_mfma_f32_16x16x32_bf16(ah[mt][kc], bh[kc], acc[mt], 0, 0, 0);
        acc[mt] = __builtin_amdgcn_mfma_f32_16x16x32_bf16(al[mt][kc], bh[kc], acc[mt], 0, 0, 0);
        acc[mt] = __builtin_amdgcn_mfma_f32_16x16x32_bf16(ah[mt][kc], bl[kc], acc[mt], 0, 0, 0);
      }
    }
    float bias = b_qkv[e];
    int which = ebase >> 8;  // wave-uniform
    if (which < 2) {
      float sc = (which == 0) ? LOG2E : 0.0625f;
      unsigned short* Dh = (which == 0) ? Qh : Kh;
      unsigned short* Dl = (which == 0) ? Ql : Kl;
      int hh = (e >> 5) & 7, dd = e & 31;
      size_t rowb = (bv * HH + hh) * TT;
      #pragma unroll
      for (int mt = 0; mt < 4; ++mt)
        #pragma unroll
        for (int reg = 0; reg < 4; ++reg) {
          int lrow = mt * 16 + quad * 4 + reg;
          // rows >= 60 would RACE with the next tt-block (zero-staged x)
          if (lrow < 60) {
            int t = t0 + lrow;
            float s = (acc[mt][reg] + bias) * sc;
            unsigned short hb = f2bf(s);
            size_t idx = (rowb + t) * HD + dd;
            Dh[idx] = hb; Dl[idx] = f2bf(s - bf2f(hb));
          }
        }
    } else {
      int ep = e - 512;
      #pragma unroll
      for (int mt = 0; mt < 4; ++mt)
        #pragma unroll
        for (int reg = 0; reg < 4; ++reg)
          sm.vtr[ep * 66 + mt * 16 + quad * 4 + reg] = f2bf(acc[mt][reg] + bias);
    }
  }
  __syncthreads();
  for (int i = tid; i < 256 * 30; i += 256) {
    int ep = i / 30, tc = (i % 30) * 2;
    int e = 512 + ep;
    int hh = (e >> 5) & 7, dd = e & 31;
    size_t idx = ((bv * HH + hh) * HD + dd) * 320 + t0 + tc;
    *(unsigned int*)&Vt[idx] = *(const unsigned int*)&sm.vtr[ep * 66 + tc];
    // Vt rows t in [300,320) stay poison (finite bf16) -> always hit P=0.
  }
}

// ---------------- Kernel B: MFMA attention, 32 rows/wave ----------------
// R5: single-variable experiment -- (256,3) -> (256,4).
// Evidence: LDS_Block_Size = 36,864 B -> 4 blocks/CU FIT by LDS (147K <= 160K);
// the only 4th-block blocker was the launch bound's register budget. At
// (256,3): 80 arch VGPR + ~16-32 AGPR ~= 110-120 total < 128 = (256,4)'s
// budget, so no spill expected (unlike R1's 128->64 halving).
// Failure signature: VGPR_Count collapses + WRITE_SIZE >> 61 MB (spill) ->
// revert. Success: occupancy 25 -> ~33%, attn ~139 -> ~115 us.
__global__ __launch_bounds__(256, 4) void attn12_kernel(
    const unsigned short* __restrict__ Qh, const unsigned short* __restrict__ Ql,
    const unsigned short* __restrict__ Kh, const unsigned short* __restrict__ Kl,
    const unsigned short* __restrict__ Vt, const unsigned short* __restrict__ btPad,
    unsigned short* __restrict__ Oh, unsigned short* __restrict__ Ol)
{
  __shared__ __align__(16) unsigned short sPh[2][128 * 72];  // 36,864 B, rows wave-private

  int bid0 = blockIdx.x;
  int bid = (bid0 & 7) * 600 + (bid0 >> 3);   // 4800 % 8 == 0 -> bijective XCD swizzle
  int lt = bid % 3; int rest = bid / 3;
  int h = rest & 7; rest >>= 3;
  int v = rest % 25; int b = rest / 25;
  int l0 = lt * 128;
  int tid = threadIdx.x;
  int w = tid >> 6, lane = tid & 63, quad = lane >> 4, c16 = lane & 15;
  if (l0 + 32 * w >= TT) return;  // fully-garbage wave: no barriers, sPh wave-private
  size_t tbase = ((size_t)(b * VV + v) * HH + h) * TT;
  size_t vbase = ((size_t)(b * VV + v) * HH + h) * HD;

  bf16x8 qh[2], qlw[2];
  #pragma unroll
  for (int mt = 0; mt < 2; ++mt) {
    size_t qo = (tbase + l0 + w * 32 + mt * 16 + c16) * HD + quad * 8;
    qh[mt]  = *(const bf16x8*)&Qh[qo];
    qlw[mt] = *(const bf16x8*)&Ql[qo];
  }

  // rt-invariant bpermute addresses + selects (per reg)
  int srcaddr[4]; bool sel[4];
  #pragma unroll
  for (int reg = 0; reg < 4; ++reg) {
    srcaddr[reg] = 4 * (quad * 16 + ((15 + 4 * quad + reg - c16) & 15));
    sel[reg] = (4 * quad + reg) > c16;   // a==4
  }

  f32x4 accO[2][2];
  #pragma unroll
  for (int mt = 0; mt < 2; ++mt)
    #pragma unroll
    for (int no = 0; no < 2; ++no)
      accO[mt][no] = (f32x4){0.f, 0.f, 0.f, 0.f};
  float psum[2][4] = {{0.f, 0.f, 0.f, 0.f}, {0.f, 0.f, 0.f, 0.f}};

  #pragma unroll
  for (int rt = 0; rt < 5; ++rt) {
    const int r0 = rt * 64;
    unsigned short* myP = &sPh[rt & 1][32 * w * 72];

    // ---- K loads (shared by both row-tiles) + V (prev tile) + 6 distinct bt tiles ----
    const unsigned short* kb = &Kh[(tbase + r0 + c16) * HD + quad * 8];
    const unsigned short* lb = &Kl[(tbase + r0 + c16) * HD + quad * 8];
    bf16x8 khv[4], klv[4];
    #pragma unroll
    for (int nt = 0; nt < 4; ++nt) {
      khv[nt] = *(const bf16x8*)&kb[nt * 16 * HD];
      klv[nt] = *(const bf16x8*)&lb[nt * 16 * HD];
    }
    bf16x8 vv[2][2];
    if (rt > 0) {
      int p0 = r0 - 64;  // previous tile's base
      #pragma unroll
      for (int kc = 0; kc < 2; ++kc)
        #pragma unroll
        for (int no = 0; no < 2; ++no)
          vv[kc][no] = *(const bf16x8*)&Vt[(vbase + no * 16 + c16) * 320 + p0 + kc * 32 + quad * 8];
    }
    // bt6[j]: rows (l0+256+32w-r0) + 16j + c16; row-tile mt uses j = mt+n5, n5=0..4
    const unsigned short* btb = &btPad[(size_t)(l0 + 256 + 32 * w - r0 + c16) * HD + quad * 8];
    bf16x8 bt6[6];
    #pragma unroll
    for (int j = 0; j < 6; ++j) bt6[j] = *(const bf16x8*)&btb[j * 16 * HD];

    // ---- per row-tile: rolling per-nt pipeline ----
    #pragma unroll
    for (int mt = 0; mt < 2; ++mt) {
      float Bhi[4], Blo[4];
      {
        f32x4 r = {0.f, 0.f, 0.f, 0.f};
        r = __builtin_amdgcn_mfma_f32_16x16x32_bf16(qh[mt], bt6[mt + 4], r, 0, 0, 0);
        #pragma unroll
        for (int reg = 0; reg < 4; ++reg) Bhi[reg] = bperm(srcaddr[reg], r[reg]);
      }
      #pragma unroll
      for (int nt = 0; nt < 4; ++nt) {
        f32x4 sc = {0.f, 0.f, 0.f, 0.f};
        sc = __builtin_amdgcn_mfma_f32_16x16x32_bf16(qh[mt],  khv[nt], sc, 0, 0, 0);
        sc = __builtin_amdgcn_mfma_f32_16x16x32_bf16(qlw[mt], khv[nt], sc, 0, 0, 0);
        sc = __builtin_amdgcn_mfma_f32_16x16x32_bf16(qh[mt],  klv[nt], sc, 0, 0, 0);
        f32x4 r = {0.f, 0.f, 0.f, 0.f};
        r = __builtin_amdgcn_mfma_f32_16x16x32_bf16(qh[mt], bt6[mt + 3 - nt], r, 0, 0, 0);
        #pragma unroll
        for (int reg = 0; reg < 4; ++reg) Blo[reg] = bperm(srcaddr[reg], r[reg]);

        bool bad = (r0 + nt * 16 + c16) >= TT;
        #pragma unroll
        for (int reg = 0; reg < 4; ++reg) {
          float ri = sel[reg] ? Bhi[reg] : Blo[reg];
          float p = bad ? 0.f : __builtin_amdgcn_exp2f(sc[reg] + ri);
          psum[mt][reg] += p;
          myP[(mt * 16 + 4 * quad + reg) * 72 + nt * 16 + c16] = f2bf(p);
        }
        #pragma unroll
        for (int reg = 0; reg < 4; ++reg) Bhi[reg] = Blo[reg];
      }
    }

    // ---- PV for PREVIOUS tile (buffer (rt-1)&1) ----
    if (rt > 0) {
      unsigned short* prevP = &sPh[(rt - 1) & 1][32 * w * 72];
      #pragma unroll
      for (int mt = 0; mt < 2; ++mt)
        #pragma unroll
        for (int kc = 0; kc < 2; ++kc) {
          bf16x8 pf = *(const bf16x8*)&prevP[(mt * 16 + c16) * 72 + kc * 32 + quad * 8];
          #pragma unroll
          for (int no = 0; no < 2; ++no)
            accO[mt][no] = __builtin_amdgcn_mfma_f32_16x16x32_bf16(pf, vv[kc][no], accO[mt][no], 0, 0, 0);
        }
    }
  }
  // ---- tail PV for rt=4 (buffer 0) ----
  {
    int p0 = 4 * 64;
    unsigned short* prevP = &sPh[0][32 * w * 72];
    #pragma unroll
    for (int kc = 0; kc < 2; ++kc) {
      bf16x8 vfr[2];
      #pragma unroll
      for (int no = 0; no < 2; ++no)
        vfr[no] = *(const bf16x8*)&Vt[(vbase + no * 16 + c16) * 320 + p0 + kc * 32 + quad * 8];
      #pragma unroll
      for (int mt = 0; mt < 2; ++mt) {
        bf16x8 pf = *(const bf16x8*)&prevP[(mt * 16 + c16) * 72 + kc * 32 + quad * 8];
        #pragma unroll
        for (int no = 0; no < 2; ++no)
          accO[mt][no] = __builtin_amdgcn_mfma_f32_16x16x32_bf16(pf, vfr[no], accO[mt][no], 0, 0, 0);
      }
    }
  }

  // ---- row-sum reduce + epilogue ----
  #pragma unroll
  for (int mt = 0; mt < 2; ++mt)
    #pragma unroll
    for (int reg = 0; reg < 4; ++reg) {
      #pragma unroll
      for (int off = 1; off <= 8; off <<= 1)
        psum[mt][reg] += __shfl_xor(psum[mt][reg], off);
    }
  size_t obase = (size_t)(b * VV + v) * TT;
  #pragma unroll
  for (int mt = 0; mt < 2; ++mt)
    #pragma unroll
    for (int no = 0; no < 2; ++no)
      #pragma unroll
      for (int reg = 0; reg < 4; ++reg) {
        int gl = l0 + 32 * w + 16 * mt + 4 * quad + reg;
        if (gl < TT) {
          float o = accO[mt][no][reg] / psum[mt][reg];
          size_t oi = (obase + gl) * EE + h * HD + no * 16 + c16;
          unsigned short hb = f2bf(o);
          Oh[oi] = hb; Ol[oi] = f2bf(o - bf2f(hb));
        }
      }
}

// ---------------- Kernel C: merge projection, 2000 blocks (t-tiles of 30) ----------------
__global__ __launch_bounds__(256, 4) void merge3_kernel(
    const unsigned short* __restrict__ Oh, const unsigned short* __restrict__ Ol,
    const unsigned short* __restrict__ WhT, const unsigned short* __restrict__ WlT,
    const float* __restrict__ b_merge, float* __restrict__ out)
{
  int blk = blockIdx.x;
  int tt = blk % 10; blk /= 10;
  int v = blk % 25; int b = blk / 25;
  int nb = b >> 1, mm = b & 1;
  int tid = threadIdx.x;
  int w = tid >> 6, lane = tid & 63, quad = lane >> 4, c16 = lane & 15;
  size_t obase = (size_t)(b * VV + v) * TT;
  int t0 = tt * 30;
  int cidx = w * 16 + c16;

  f32x4 acc[2];
  acc[0] = (f32x4){0.f, 0.f, 0.f, 0.f};
  acc[1] = (f32x4){0.f, 0.f, 0.f, 0.f};

  for (int ks = 0; ks < 8; ++ks) {
    int eoff = ks * 32 + quad * 8;
    bf16x8 bh = *(const bf16x8*)&WhT[(size_t)cidx * EE + eoff];
    bf16x8 bl = *(const bf16x8*)&WlT[(size_t)cidx * EE + eoff];
    bf16x8 ahv[2], alv[2];
    #pragma unroll
    for (int mt = 0; mt < 2; ++mt) {
      size_t ao = (obase + t0 + mt * 16 + c16) * EE + eoff;
      ahv[mt] = *(const bf16x8*)&Oh[ao];
      alv[mt] = *(const bf16x8*)&Ol[ao];
    }
    #pragma unroll
    for (int mt = 0; mt < 2; ++mt) {
      acc[mt] = __builtin_amdgcn_mfma_f32_16x16x32_bf16(ahv[mt], bh, acc[mt], 0, 0, 0);
      acc[mt] = __builtin_amdgcn_mfma_f32_16x16x32_bf16(alv[mt], bh, acc[mt], 0, 0, 0);
      acc[mt] = __builtin_amdgcn_mfma_f32_16x16x32_bf16(ahv[mt], bl, acc[mt], 0, 0, 0);
    }
  }
  float bm = b_merge[cidx];
  #pragma unroll
  for (int mt = 0; mt < 2; ++mt)
    #pragma unroll
    for (int reg = 0; reg < 4; ++reg) {
      int lrow = mt * 16 + 4 * quad + reg;
      if (lrow < 30) {
        int t = t0 + lrow;
        out[(((size_t)nb * CC + cidx) * VV + v) * TT * MM + (size_t)t * MM + mm]
            = acc[mt][reg] + bm;
      }
    }
}

extern "C" void kernel_launch(void* const* d_in, const int* in_sizes, int n_in,
                              void* d_out, int out_size, void* d_ws, size_t ws_size,
                              hipStream_t stream) {
  const float* x          = (const float*)d_in[0];
  const float* w_qkv      = (const float*)d_in[1];
  const float* b_qkv      = (const float*)d_in[2];
  const float* w_merge    = (const float*)d_in[3];
  const float* b_merge    = (const float*)d_in[4];
  const float* bias_table = (const float*)d_in[5];
  float* out = (float*)d_out;
  unsigned short* ws16 = (unsigned short*)d_ws;
  unsigned short* Qh   = ws16;
  unsigned short* Ql   = ws16 + (size_t)QKN;
  unsigned short* Kh   = ws16 + (size_t)2 * QKN;
  unsigned short* Kl   = ws16 + (size_t)3 * QKN;
  unsigned short* Vt   = ws16 + (size_t)4 * QKN;
  unsigned short* Oh   = ws16 + (size_t)4 * QKN + VTN;
  unsigned short* Ol   = ws16 + (size_t)5 * QKN + VTN;
  unsigned short* base8 = ws16 + (size_t)6 * QKN + VTN;
  unsigned short* WhT  = base8;
  unsigned short* WlT  = base8 + 16384;
  unsigned short* WqTh = base8 + 32768;
  unsigned short* WqTl = base8 + 81920;
  unsigned short* btPad = base8 + 131072;

  prep_kernel<<<dim3(344), dim3(256), 0, stream>>>(w_qkv, w_merge, bias_table,
                                                   WqTh, WqTl, WhT, WlT, btPad);
  qkv_kernel<<<dim3(1000), dim3(256), 0, stream>>>(x, b_qkv, WqTh, WqTl,
                                                   Qh, Ql, Kh, Kl, Vt);
  attn12_kernel<<<dim3(4800), dim3(256), 0, stream>>>(Qh, Ql, Kh, Kl, Vt, btPad, Oh, Ol);
  merge3_kernel<<<dim3(2000), dim3(256), 0, stream>>>(Oh, Ol, WhT, WlT, b_merge, out);
}

// Round 7
// 326.226 us; speedup vs baseline: 1.2071x; 1.2071x over previous
//
#include <hip/hip_runtime.h>
#include <cstdint>

#define NN 4
#define CC 64
#define VV 25
#define TT 300
#define MM 2
#define HH 8
#define HD 32
#define EE 256

typedef short bf16x8 __attribute__((ext_vector_type(8)));
typedef float f32x4 __attribute__((ext_vector_type(4)));

__device__ __forceinline__ unsigned short f2bf(float f) {
  union { float f; unsigned u; } x; x.f = f;
  unsigned r = x.u + 0x7FFF + ((x.u >> 16) & 1);  // RNE
  return (unsigned short)(r >> 16);
}
__device__ __forceinline__ float bf2f(unsigned short s) {
  union { unsigned u; float f; } x; x.u = ((unsigned)s) << 16;
  return x.f;
}
__device__ __forceinline__ float bperm(int byteaddr, float v) {
  return __int_as_float(__builtin_amdgcn_ds_bpermute(byteaddr, __float_as_int(v)));
}

// ws layout (unsigned short units):
//   Qh,Ql,Kh,Kl : [b,v,h,t<300,d] (15,360,000 each) [Q xlog2e, K x1/16]
//   Vt : [b,v,h,d][t pad 320] (16,384,000)
//   Oh,Ol : [b,v,t<300,e] (15,360,000 each)
//   WhT,WlT [c][e] (16,384 each); WqTh,WqTl [e][c] (49,152 each);
//   btPad [704][32] bf16, rows 20..618 = bias_table, else 0 (22,528)
#define QKN 15360000
#define VTN 16384000
#define LOG2E 1.4426950408889634f

// ---------------- prep: transpose/split weights + bf16 bias table ----------------
__global__ __launch_bounds__(256) void prep_kernel(
    const float* __restrict__ w_qkv, const float* __restrict__ w_merge,
    const float* __restrict__ bias_table,
    unsigned short* __restrict__ WqTh, unsigned short* __restrict__ WqTl,
    unsigned short* __restrict__ WhT, unsigned short* __restrict__ WlT,
    unsigned short* __restrict__ btPad)
{
  int i = blockIdx.x * 256 + threadIdx.x;
  if (i < 49152) {                      // w_qkv [c][768] -> [e][c] hi/lo
    int c = i / 768, e = i % 768;
    float v = w_qkv[i];
    unsigned short hb = f2bf(v);
    WqTh[e * 64 + c] = hb; WqTl[e * 64 + c] = f2bf(v - bf2f(hb));
  } else if (i < 65536) {               // w_merge [e][64] -> [c][e] hi/lo
    int j = i - 49152;
    int e = j >> 6, c = j & 63;
    float v = w_merge[j];
    unsigned short hb = f2bf(v);
    WhT[c * EE + e] = hb; WlT[c * EE + e] = f2bf(v - bf2f(hb));
  } else if (i < 65536 + 22528) {       // bias_table -> padded bf16 [704][32]
    int j = i - 65536;
    int row = j >> 5, d = j & 31;
    int g = row - 20;
    float v = (g >= 0 && g < 2 * TT - 1) ? bias_table[g * 32 + d] : 0.f;
    btPad[j] = f2bf(v);
  }
}

// ---------------- Kernel A: QKV projection via MFMA (unchanged, known-good) ----------------
__global__ __launch_bounds__(256, 3) void qkv_kernel(
    const float* __restrict__ x, const float* __restrict__ b_qkv,
    const unsigned short* __restrict__ WqTh, const unsigned short* __restrict__ WqTl,
    unsigned short* __restrict__ Qh, unsigned short* __restrict__ Ql,
    unsigned short* __restrict__ Kh, unsigned short* __restrict__ Kl,
    unsigned short* __restrict__ Vt)
{
  __shared__ union {
    float a[64 * 69];             // sA[c][t], stride 69
    unsigned short vtr[256 * 66]; // V transpose buffer [e'][t]
  } sm;

  int blk = blockIdx.x;
  int tt = blk % 5; blk /= 5;
  int v25 = blk % 25; int b = blk / 25;
  int n = b >> 1, m = b & 1;
  int t0 = tt * 60;
  int tid = threadIdx.x;
  int w = tid >> 6, lane = tid & 63, quad = lane >> 4, c16 = lane & 15;

  for (int i = tid; i < 64 * 64; i += 256) {
    int c = i >> 6, t = i & 63;
    float val = 0.f;
    if (t < 60) val = x[((((size_t)n * CC + c) * VV + v25) * TT + (t0 + t)) * MM + m];
    sm.a[c * 69 + t] = val;
  }
  __syncthreads();

  bf16x8 ah[4][2], al[4][2];
  #pragma unroll
  for (int mt = 0; mt < 4; ++mt)
    #pragma unroll
    for (int kc = 0; kc < 2; ++kc)
      #pragma unroll
      for (int j = 0; j < 8; ++j) {
        float f = sm.a[(kc * 32 + quad * 8 + j) * 69 + mt * 16 + c16];
        unsigned short hb = f2bf(f);
        ah[mt][kc][j] = (short)hb;
        al[mt][kc][j] = (short)f2bf(f - bf2f(hb));
      }
  __syncthreads();  // sA dead; sVt (union) may be written

  size_t bv = (size_t)(b * VV + v25);
  int e0 = w * 192;
  for (int nt = 0; nt < 12; ++nt) {
    int ebase = e0 + nt * 16;
    int e = ebase + c16;
    bf16x8 bh[2], bl[2];
    #pragma unroll
    for (int kc = 0; kc < 2; ++kc) {
      bh[kc] = *(const bf16x8*)&WqTh[(size_t)e * 64 + kc * 32 + quad * 8];
      bl[kc] = *(const bf16x8*)&WqTl[(size_t)e * 64 + kc * 32 + quad * 8];
    }
    f32x4 acc[4];
    #pragma unroll
    for (int mt = 0; mt < 4; ++mt) {
      acc[mt] = (f32x4){0.f, 0.f, 0.f, 0.f};
      #pragma unroll
      for (int kc = 0; kc < 2; ++kc) {
        acc[mt] = __builtin_amdgcn_mfma_f32_16x16x32_bf16(ah[mt][kc], bh[kc], acc[mt], 0, 0, 0);
        acc[mt] = __builtin_amdgcn_mfma_f32_16x16x32_bf16(al[mt][kc], bh[kc], acc[mt], 0, 0, 0);
        acc[mt] = __builtin_amdgcn_mfma_f32_16x16x32_bf16(ah[mt][kc], bl[kc], acc[mt], 0, 0, 0);
      }
    }
    float bias = b_qkv[e];
    int which = ebase >> 8;  // wave-uniform
    if (which < 2) {
      float sc = (which == 0) ? LOG2E : 0.0625f;
      unsigned short* Dh = (which == 0) ? Qh : Kh;
      unsigned short* Dl = (which == 0) ? Ql : Kl;
      int hh = (e >> 5) & 7, dd = e & 31;
      size_t rowb = (bv * HH + hh) * TT;
      #pragma unroll
      for (int mt = 0; mt < 4; ++mt)
        #pragma unroll
        for (int reg = 0; reg < 4; ++reg) {
          int lrow = mt * 16 + quad * 4 + reg;
          // rows >= 60 would RACE with the next tt-block (zero-staged x)
          if (lrow < 60) {
            int t = t0 + lrow;
            float s = (acc[mt][reg] + bias) * sc;
            unsigned short hb = f2bf(s);
            size_t idx = (rowb + t) * HD + dd;
            Dh[idx] = hb; Dl[idx] = f2bf(s - bf2f(hb));
          }
        }
    } else {
      int ep = e - 512;
      #pragma unroll
      for (int mt = 0; mt < 4; ++mt)
        #pragma unroll
        for (int reg = 0; reg < 4; ++reg)
          sm.vtr[ep * 66 + mt * 16 + quad * 4 + reg] = f2bf(acc[mt][reg] + bias);
    }
  }
  __syncthreads();
  for (int i = tid; i < 256 * 30; i += 256) {
    int ep = i / 30, tc = (i % 30) * 2;
    int e = 512 + ep;
    int hh = (e >> 5) & 7, dd = e & 31;
    size_t idx = ((bv * HH + hh) * HD + dd) * 320 + t0 + tc;
    *(unsigned int*)&Vt[idx] = *(const unsigned int*)&sm.vtr[ep * 66 + tc];
    // Vt rows t in [300,320) stay poison (finite bf16) -> always hit P=0.
  }
}

// ---------------- Kernel B: MFMA attention, 32 rows/wave ----------------
// R6: revert R5's (256,4) spill disaster (VGPR 80->64, WRITE 61->349MB, 139->209us).
// New facts from R4/R5: at (256,3) the HW fits only 2 blocks/CU (Occupancy 25%
// = 8 waves/CU) -- the 3rd wave's register slot is unreachable (alloc
// granularity rounds ~170 live regs up). So (256,2) costs ZERO occupancy and
// doubles the register budget to 256. That budget is what R0's K-prefetch
// lacked (compiler sank the dbuf at 64-reg headroom). Changes vs R4:
//  1. launch_bounds (256,3) -> (256,2)  [no occupancy change possible]
//  2. K register double-buffer restored: prefetch K(rt+1) at top of rt,
//     consume khv[cb] loaded one iteration earlier (~2-3K cycles slack).
// Tells: VGPR stays ~80 -> compiler sank prefetch again (lever dead);
// WRITE >> 61MB -> spill -> revert to exact R4.
__global__ __launch_bounds__(256, 2) void attn13_kernel(
    const unsigned short* __restrict__ Qh, const unsigned short* __restrict__ Ql,
    const unsigned short* __restrict__ Kh, const unsigned short* __restrict__ Kl,
    const unsigned short* __restrict__ Vt, const unsigned short* __restrict__ btPad,
    unsigned short* __restrict__ Oh, unsigned short* __restrict__ Ol)
{
  __shared__ __align__(16) unsigned short sPh[2][128 * 72];  // 36,864 B, rows wave-private

  int bid0 = blockIdx.x;
  int bid = (bid0 & 7) * 600 + (bid0 >> 3);   // 4800 % 8 == 0 -> bijective XCD swizzle
  int lt = bid % 3; int rest = bid / 3;
  int h = rest & 7; rest >>= 3;
  int v = rest % 25; int b = rest / 25;
  int l0 = lt * 128;
  int tid = threadIdx.x;
  int w = tid >> 6, lane = tid & 63, quad = lane >> 4, c16 = lane & 15;
  if (l0 + 32 * w >= TT) return;  // fully-garbage wave: no barriers, sPh wave-private
  size_t tbase = ((size_t)(b * VV + v) * HH + h) * TT;
  size_t vbase = ((size_t)(b * VV + v) * HH + h) * HD;

  bf16x8 qh[2], qlw[2];
  #pragma unroll
  for (int mt = 0; mt < 2; ++mt) {
    size_t qo = (tbase + l0 + w * 32 + mt * 16 + c16) * HD + quad * 8;
    qh[mt]  = *(const bf16x8*)&Qh[qo];
    qlw[mt] = *(const bf16x8*)&Ql[qo];
  }

  // rt-invariant bpermute addresses + selects (per reg)
  int srcaddr[4]; bool sel[4];
  #pragma unroll
  for (int reg = 0; reg < 4; ++reg) {
    srcaddr[reg] = 4 * (quad * 16 + ((15 + 4 * quad + reg - c16) & 15));
    sel[reg] = (4 * quad + reg) > c16;   // a==4
  }

  // ---- K double buffer: preload tile 0 into buf 0 ----
  bf16x8 khv[2][4], klv[2][4];
  {
    const unsigned short* kb = &Kh[(tbase + c16) * HD + quad * 8];
    const unsigned short* lb = &Kl[(tbase + c16) * HD + quad * 8];
    #pragma unroll
    for (int nt = 0; nt < 4; ++nt) {
      khv[0][nt] = *(const bf16x8*)&kb[nt * 16 * HD];
      klv[0][nt] = *(const bf16x8*)&lb[nt * 16 * HD];
    }
  }

  f32x4 accO[2][2];
  #pragma unroll
  for (int mt = 0; mt < 2; ++mt)
    #pragma unroll
    for (int no = 0; no < 2; ++no)
      accO[mt][no] = (f32x4){0.f, 0.f, 0.f, 0.f};
  float psum[2][4] = {{0.f, 0.f, 0.f, 0.f}, {0.f, 0.f, 0.f, 0.f}};

  #pragma unroll
  for (int rt = 0; rt < 5; ++rt) {
    const int r0 = rt * 64;
    const int cb = rt & 1, nb = cb ^ 1;
    unsigned short* myP = &sPh[rt & 1][32 * w * 72];

    // ---- prefetch K for NEXT tile + V (prev tile) + 6 distinct bt tiles ----
    if (rt < 4) {
      const unsigned short* kb = &Kh[(tbase + r0 + 64 + c16) * HD + quad * 8];
      const unsigned short* lb = &Kl[(tbase + r0 + 64 + c16) * HD + quad * 8];
      #pragma unroll
      for (int nt = 0; nt < 4; ++nt) {
        khv[nb][nt] = *(const bf16x8*)&kb[nt * 16 * HD];
        klv[nb][nt] = *(const bf16x8*)&lb[nt * 16 * HD];
      }
    }
    bf16x8 vv[2][2];
    if (rt > 0) {
      int p0 = r0 - 64;  // previous tile's base
      #pragma unroll
      for (int kc = 0; kc < 2; ++kc)
        #pragma unroll
        for (int no = 0; no < 2; ++no)
          vv[kc][no] = *(const bf16x8*)&Vt[(vbase + no * 16 + c16) * 320 + p0 + kc * 32 + quad * 8];
    }
    // bt6[j]: rows (l0+256+32w-r0) + 16j + c16; row-tile mt uses j = mt+n5, n5=0..4
    const unsigned short* btb = &btPad[(size_t)(l0 + 256 + 32 * w - r0 + c16) * HD + quad * 8];
    bf16x8 bt6[6];
    #pragma unroll
    for (int j = 0; j < 6; ++j) bt6[j] = *(const bf16x8*)&btb[j * 16 * HD];

    // ---- per row-tile: rolling per-nt pipeline (K from buffer cb) ----
    #pragma unroll
    for (int mt = 0; mt < 2; ++mt) {
      float Bhi[4], Blo[4];
      {
        f32x4 r = {0.f, 0.f, 0.f, 0.f};
        r = __builtin_amdgcn_mfma_f32_16x16x32_bf16(qh[mt], bt6[mt + 4], r, 0, 0, 0);
        #pragma unroll
        for (int reg = 0; reg < 4; ++reg) Bhi[reg] = bperm(srcaddr[reg], r[reg]);
      }
      #pragma unroll
      for (int nt = 0; nt < 4; ++nt) {
        f32x4 sc = {0.f, 0.f, 0.f, 0.f};
        sc = __builtin_amdgcn_mfma_f32_16x16x32_bf16(qh[mt],  khv[cb][nt], sc, 0, 0, 0);
        sc = __builtin_amdgcn_mfma_f32_16x16x32_bf16(qlw[mt], khv[cb][nt], sc, 0, 0, 0);
        sc = __builtin_amdgcn_mfma_f32_16x16x32_bf16(qh[mt],  klv[cb][nt], sc, 0, 0, 0);
        f32x4 r = {0.f, 0.f, 0.f, 0.f};
        r = __builtin_amdgcn_mfma_f32_16x16x32_bf16(qh[mt], bt6[mt + 3 - nt], r, 0, 0, 0);
        #pragma unroll
        for (int reg = 0; reg < 4; ++reg) Blo[reg] = bperm(srcaddr[reg], r[reg]);

        bool bad = (r0 + nt * 16 + c16) >= TT;
        #pragma unroll
        for (int reg = 0; reg < 4; ++reg) {
          float ri = sel[reg] ? Bhi[reg] : Blo[reg];
          float p = bad ? 0.f : __builtin_amdgcn_exp2f(sc[reg] + ri);
          psum[mt][reg] += p;
          myP[(mt * 16 + 4 * quad + reg) * 72 + nt * 16 + c16] = f2bf(p);
        }
        #pragma unroll
        for (int reg = 0; reg < 4; ++reg) Bhi[reg] = Blo[reg];
      }
    }

    // ---- PV for PREVIOUS tile (buffer (rt-1)&1) ----
    if (rt > 0) {
      unsigned short* prevP = &sPh[(rt - 1) & 1][32 * w * 72];
      #pragma unroll
      for (int mt = 0; mt < 2; ++mt)
        #pragma unroll
        for (int kc = 0; kc < 2; ++kc) {
          bf16x8 pf = *(const bf16x8*)&prevP[(mt * 16 + c16) * 72 + kc * 32 + quad * 8];
          #pragma unroll
          for (int no = 0; no < 2; ++no)
            accO[mt][no] = __builtin_amdgcn_mfma_f32_16x16x32_bf16(pf, vv[kc][no], accO[mt][no], 0, 0, 0);
        }
    }
  }
  // ---- tail PV for rt=4 (buffer 0) ----
  {
    int p0 = 4 * 64;
    unsigned short* prevP = &sPh[0][32 * w * 72];
    #pragma unroll
    for (int kc = 0; kc < 2; ++kc) {
      bf16x8 vfr[2];
      #pragma unroll
      for (int no = 0; no < 2; ++no)
        vfr[no] = *(const bf16x8*)&Vt[(vbase + no * 16 + c16) * 320 + p0 + kc * 32 + quad * 8];
      #pragma unroll
      for (int mt = 0; mt < 2; ++mt) {
        bf16x8 pf = *(const bf16x8*)&prevP[(mt * 16 + c16) * 72 + kc * 32 + quad * 8];
        #pragma unroll
        for (int no = 0; no < 2; ++no)
          accO[mt][no] = __builtin_amdgcn_mfma_f32_16x16x32_bf16(pf, vfr[no], accO[mt][no], 0, 0, 0);
      }
    }
  }

  // ---- row-sum reduce + epilogue ----
  #pragma unroll
  for (int mt = 0; mt < 2; ++mt)
    #pragma unroll
    for (int reg = 0; reg < 4; ++reg) {
      #pragma unroll
      for (int off = 1; off <= 8; off <<= 1)
        psum[mt][reg] += __shfl_xor(psum[mt][reg], off);
    }
  size_t obase = (size_t)(b * VV + v) * TT;
  #pragma unroll
  for (int mt = 0; mt < 2; ++mt)
    #pragma unroll
    for (int no = 0; no < 2; ++no)
      #pragma unroll
      for (int reg = 0; reg < 4; ++reg) {
        int gl = l0 + 32 * w + 16 * mt + 4 * quad + reg;
        if (gl < TT) {
          float o = accO[mt][no][reg] / psum[mt][reg];
          size_t oi = (obase + gl) * EE + h * HD + no * 16 + c16;
          unsigned short hb = f2bf(o);
          Oh[oi] = hb; Ol[oi] = f2bf(o - bf2f(hb));
        }
      }
}

// ---------------- Kernel C: merge projection, 2000 blocks (t-tiles of 30) ----------------
__global__ __launch_bounds__(256, 4) void merge3_kernel(
    const unsigned short* __restrict__ Oh, const unsigned short* __restrict__ Ol,
    const unsigned short* __restrict__ WhT, const unsigned short* __restrict__ WlT,
    const float* __restrict__ b_merge, float* __restrict__ out)
{
  int blk = blockIdx.x;
  int tt = blk % 10; blk /= 10;
  int v = blk % 25; int b = blk / 25;
  int nb = b >> 1, mm = b & 1;
  int tid = threadIdx.x;
  int w = tid >> 6, lane = tid & 63, quad = lane >> 4, c16 = lane & 15;
  size_t obase = (size_t)(b * VV + v) * TT;
  int t0 = tt * 30;
  int cidx = w * 16 + c16;

  f32x4 acc[2];
  acc[0] = (f32x4){0.f, 0.f, 0.f, 0.f};
  acc[1] = (f32x4){0.f, 0.f, 0.f, 0.f};

  for (int ks = 0; ks < 8; ++ks) {
    int eoff = ks * 32 + quad * 8;
    bf16x8 bh = *(const bf16x8*)&WhT[(size_t)cidx * EE + eoff];
    bf16x8 bl = *(const bf16x8*)&WlT[(size_t)cidx * EE + eoff];
    bf16x8 ahv[2], alv[2];
    #pragma unroll
    for (int mt = 0; mt < 2; ++mt) {
      size_t ao = (obase + t0 + mt * 16 + c16) * EE + eoff;
      ahv[mt] = *(const bf16x8*)&Oh[ao];
      alv[mt] = *(const bf16x8*)&Ol[ao];
    }
    #pragma unroll
    for (int mt = 0; mt < 2; ++mt) {
      acc[mt] = __builtin_amdgcn_mfma_f32_16x16x32_bf16(ahv[mt], bh, acc[mt], 0, 0, 0);
      acc[mt] = __builtin_amdgcn_mfma_f32_16x16x32_bf16(alv[mt], bh, acc[mt], 0, 0, 0);
      acc[mt] = __builtin_amdgcn_mfma_f32_16x16x32_bf16(ahv[mt], bl, acc[mt], 0, 0, 0);
    }
  }
  float bm = b_merge[cidx];
  #pragma unroll
  for (int mt = 0; mt < 2; ++mt)
    #pragma unroll
    for (int reg = 0; reg < 4; ++reg) {
      int lrow = mt * 16 + 4 * quad + reg;
      if (lrow < 30) {
        int t = t0 + lrow;
        out[(((size_t)nb * CC + cidx) * VV + v) * TT * MM + (size_t)t * MM + mm]
            = acc[mt][reg] + bm;
      }
    }
}

extern "C" void kernel_launch(void* const* d_in, const int* in_sizes, int n_in,
                              void* d_out, int out_size, void* d_ws, size_t ws_size,
                              hipStream_t stream) {
  const float* x          = (const float*)d_in[0];
  const float* w_qkv      = (const float*)d_in[1];
  const float* b_qkv      = (const float*)d_in[2];
  const float* w_merge    = (const float*)d_in[3];
  const float* b_merge    = (const float*)d_in[4];
  const float* bias_table = (const float*)d_in[5];
  float* out = (float*)d_out;
  unsigned short* ws16 = (unsigned short*)d_ws;
  unsigned short* Qh   = ws16;
  unsigned short* Ql   = ws16 + (size_t)QKN;
  unsigned short* Kh   = ws16 + (size_t)2 * QKN;
  unsigned short* Kl   = ws16 + (size_t)3 * QKN;
  unsigned short* Vt   = ws16 + (size_t)4 * QKN;
  unsigned short* Oh   = ws16 + (size_t)4 * QKN + VTN;
  unsigned short* Ol   = ws16 + (size_t)5 * QKN + VTN;
  unsigned short* base8 = ws16 + (size_t)6 * QKN + VTN;
  unsigned short* WhT  = base8;
  unsigned short* WlT  = base8 + 16384;
  unsigned short* WqTh = base8 + 32768;
  unsigned short* WqTl = base8 + 81920;
  unsigned short* btPad = base8 + 131072;

  prep_kernel<<<dim3(344), dim3(256), 0, stream>>>(w_qkv, w_merge, bias_table,
                                                   WqTh, WqTl, WhT, WlT, btPad);
  qkv_kernel<<<dim3(1000), dim3(256), 0, stream>>>(x, b_qkv, WqTh, WqTl,
                                                   Qh, Ql, Kh, Kl, Vt);
  attn13_kernel<<<dim3(4800), dim3(256), 0, stream>>>(Qh, Ql, Kh, Kl, Vt, btPad, Oh, Ol);
  merge3_kernel<<<dim3(2000), dim3(256), 0, stream>>>(Oh, Ol, WhT, WlT, b_merge, out);
}

// Round 8
// 316.010 us; speedup vs baseline: 1.2462x; 1.0323x over previous
//
#include <hip/hip_runtime.h>
#include <cstdint>

#define NN 4
#define CC 64
#define VV 25
#define TT 300
#define MM 2
#define HH 8
#define HD 32
#define EE 256

typedef short bf16x8 __attribute__((ext_vector_type(8)));
typedef float f32x4 __attribute__((ext_vector_type(4)));
typedef unsigned int u32x4 __attribute__((ext_vector_type(4)));

__device__ __forceinline__ unsigned short f2bf(float f) {
  union { float f; unsigned u; } x; x.f = f;
  unsigned r = x.u + 0x7FFF + ((x.u >> 16) & 1);  // RNE
  return (unsigned short)(r >> 16);
}
__device__ __forceinline__ float bf2f(unsigned short s) {
  union { unsigned u; float f; } x; x.u = ((unsigned)s) << 16;
  return x.f;
}
__device__ __forceinline__ float bperm(int byteaddr, float v) {
  return __int_as_float(__builtin_amdgcn_ds_bpermute(byteaddr, __float_as_int(v)));
}

// ws layout (unsigned short units):
//   Qh,Ql,Kh,Kl : [b,v,h,t<300,d] (15,360,000 each) [Q xlog2e, K x1/16]
//   Vt : [b,v,h,d][t pad 320] (16,384,000)
//   Oh,Ol : [b,v,t<300,e] (15,360,000 each)
//   WhT,WlT [c][e] (16,384 each); WqTh,WqTl [e][c] (49,152 each);
//   btPad [704][32] bf16, rows 20..618 = bias_table, else 0 (22,528)
#define QKN 15360000
#define VTN 16384000
#define LOG2E 1.4426950408889634f

// ---------------- prep: transpose/split weights + bf16 bias table ----------------
__global__ __launch_bounds__(256) void prep_kernel(
    const float* __restrict__ w_qkv, const float* __restrict__ w_merge,
    const float* __restrict__ bias_table,
    unsigned short* __restrict__ WqTh, unsigned short* __restrict__ WqTl,
    unsigned short* __restrict__ WhT, unsigned short* __restrict__ WlT,
    unsigned short* __restrict__ btPad)
{
  int i = blockIdx.x * 256 + threadIdx.x;
  if (i < 49152) {                      // w_qkv [c][768] -> [e][c] hi/lo
    int c = i / 768, e = i % 768;
    float v = w_qkv[i];
    unsigned short hb = f2bf(v);
    WqTh[e * 64 + c] = hb; WqTl[e * 64 + c] = f2bf(v - bf2f(hb));
  } else if (i < 65536) {               // w_merge [e][64] -> [c][e] hi/lo
    int j = i - 49152;
    int e = j >> 6, c = j & 63;
    float v = w_merge[j];
    unsigned short hb = f2bf(v);
    WhT[c * EE + e] = hb; WlT[c * EE + e] = f2bf(v - bf2f(hb));
  } else if (i < 65536 + 22528) {       // bias_table -> padded bf16 [704][32]
    int j = i - 65536;
    int row = j >> 5, d = j & 31;
    int g = row - 20;
    float v = (g >= 0 && g < 2 * TT - 1) ? bias_table[g * 32 + d] : 0.f;
    btPad[j] = f2bf(v);
  }
}

// ---------------- Kernel A: QKV projection via MFMA ----------------
// R7 change (theory: qkv fragment prep was 64 scalar ds_read_b32 + ~384 VALU
// f2bf ops PER THREAD, and all 4 waves redundantly converted the same 64x64
// tile -- fragment row depends on c16 only, not w):
//   * convert x->bf16 hi/lo ONCE at staging (16 elems/thread), store packed
//     (hi<<16)|lo u32 in LDS TRANSPOSED [t][c], stride 68 (keeps every
//     fragment address 16B-aligned: 68,32,8 all mult of 4 u32; read banks
//     2-way = free; staging-write 8-way conflict on 16 stores/thread = noise).
//   * fragment read: 2x ds_read_b128 per (mt,kc) + plain shift/mask unpack
//     (no asm -- R3 lesson). 16 b128 reads + ~160 VALU vs 64 b32 + ~384 VALU.
__global__ __launch_bounds__(256, 3) void qkv_kernel(
    const float* __restrict__ x, const float* __restrict__ b_qkv,
    const unsigned short* __restrict__ WqTh, const unsigned short* __restrict__ WqTl,
    unsigned short* __restrict__ Qh, unsigned short* __restrict__ Ql,
    unsigned short* __restrict__ Kh, unsigned short* __restrict__ Kl,
    unsigned short* __restrict__ Vt)
{
  __shared__ __align__(16) union {
    unsigned int a[64 * 68];      // sA2[t][c] packed (hi<<16)|lo, stride 68
    unsigned short vtr[256 * 66]; // V transpose buffer [e'][t]
  } sm;

  int blk = blockIdx.x;
  int tt = blk % 5; blk /= 5;
  int v25 = blk % 25; int b = blk / 25;
  int n = b >> 1, m = b & 1;
  int t0 = tt * 60;
  int tid = threadIdx.x;
  int w = tid >> 6, lane = tid & 63, quad = lane >> 4, c16 = lane & 15;

  for (int i = tid; i < 64 * 64; i += 256) {
    int c = i >> 6, t = i & 63;
    float val = 0.f;
    if (t < 60) val = x[((((size_t)n * CC + c) * VV + v25) * TT + (t0 + t)) * MM + m];
    unsigned short hb = f2bf(val);
    unsigned short lb = f2bf(val - bf2f(hb));
    sm.a[t * 68 + c] = ((unsigned)hb << 16) | (unsigned)lb;
  }
  __syncthreads();

  bf16x8 ah[4][2], al[4][2];
  #pragma unroll
  for (int mt = 0; mt < 4; ++mt)
    #pragma unroll
    for (int kc = 0; kc < 2; ++kc) {
      const u32x4* p = (const u32x4*)&sm.a[(mt * 16 + c16) * 68 + kc * 32 + quad * 8];
      u32x4 u0 = p[0], u1 = p[1];
      unsigned e0 = u0[0], e1 = u0[1], e2 = u0[2], e3 = u0[3];
      unsigned e4 = u1[0], e5 = u1[1], e6 = u1[2], e7 = u1[3];
      union { unsigned u[4]; bf16x8 v; } H, L;
      H.u[0] = (e1 & 0xFFFF0000u) | (e0 >> 16);
      H.u[1] = (e3 & 0xFFFF0000u) | (e2 >> 16);
      H.u[2] = (e5 & 0xFFFF0000u) | (e4 >> 16);
      H.u[3] = (e7 & 0xFFFF0000u) | (e6 >> 16);
      L.u[0] = (e1 << 16) | (e0 & 0xFFFFu);
      L.u[1] = (e3 << 16) | (e2 & 0xFFFFu);
      L.u[2] = (e5 << 16) | (e4 & 0xFFFFu);
      L.u[3] = (e7 << 16) | (e6 & 0xFFFFu);
      ah[mt][kc] = H.v;
      al[mt][kc] = L.v;
    }
  __syncthreads();  // sA dead; sVt (union) may be written

  size_t bv = (size_t)(b * VV + v25);
  int e0w = w * 192;
  for (int nt = 0; nt < 12; ++nt) {
    int ebase = e0w + nt * 16;
    int e = ebase + c16;
    bf16x8 bh[2], bl[2];
    #pragma unroll
    for (int kc = 0; kc < 2; ++kc) {
      bh[kc] = *(const bf16x8*)&WqTh[(size_t)e * 64 + kc * 32 + quad * 8];
      bl[kc] = *(const bf16x8*)&WqTl[(size_t)e * 64 + kc * 32 + quad * 8];
    }
    f32x4 acc[4];
    #pragma unroll
    for (int mt = 0; mt < 4; ++mt) {
      acc[mt] = (f32x4){0.f, 0.f, 0.f, 0.f};
      #pragma unroll
      for (int kc = 0; kc < 2; ++kc) {
        acc[mt] = __builtin_amdgcn_mfma_f32_16x16x32_bf16(ah[mt][kc], bh[kc], acc[mt], 0, 0, 0);
        acc[mt] = __builtin_amdgcn_mfma_f32_16x16x32_bf16(al[mt][kc], bh[kc], acc[mt], 0, 0, 0);
        acc[mt] = __builtin_amdgcn_mfma_f32_16x16x32_bf16(ah[mt][kc], bl[kc], acc[mt], 0, 0, 0);
      }
    }
    float bias = b_qkv[e];
    int which = ebase >> 8;  // wave-uniform
    if (which < 2) {
      float sc = (which == 0) ? LOG2E : 0.0625f;
      unsigned short* Dh = (which == 0) ? Qh : Kh;
      unsigned short* Dl = (which == 0) ? Ql : Kl;
      int hh = (e >> 5) & 7, dd = e & 31;
      size_t rowb = (bv * HH + hh) * TT;
      #pragma unroll
      for (int mt = 0; mt < 4; ++mt)
        #pragma unroll
        for (int reg = 0; reg < 4; ++reg) {
          int lrow = mt * 16 + quad * 4 + reg;
          // rows >= 60 would RACE with the next tt-block (zero-staged x)
          if (lrow < 60) {
            int t = t0 + lrow;
            float s = (acc[mt][reg] + bias) * sc;
            unsigned short hb = f2bf(s);
            size_t idx = (rowb + t) * HD + dd;
            Dh[idx] = hb; Dl[idx] = f2bf(s - bf2f(hb));
          }
        }
    } else {
      int ep = e - 512;
      #pragma unroll
      for (int mt = 0; mt < 4; ++mt)
        #pragma unroll
        for (int reg = 0; reg < 4; ++reg)
          sm.vtr[ep * 66 + mt * 16 + quad * 4 + reg] = f2bf(acc[mt][reg] + bias);
    }
  }
  __syncthreads();
  for (int i = tid; i < 256 * 30; i += 256) {
    int ep = i / 30, tc = (i % 30) * 2;
    int e = 512 + ep;
    int hh = (e >> 5) & 7, dd = e & 31;
    size_t idx = ((bv * HH + hh) * HD + dd) * 320 + t0 + tc;
    *(unsigned int*)&Vt[idx] = *(const unsigned int*)&sm.vtr[ep * 66 + tc];
    // Vt rows t in [300,320) stay poison (finite bf16) -> always hit P=0.
  }
}

// ---------------- Kernel B: MFMA attention, 32 rows/wave (R4-exact revert) ----------------
// R6 post-mortem: (256,2)+K-dbuf kept the prefetch (VGPR 128, no spill) but
// LOST a resident block (Occ 25->17.8%) and regressed 139->177us -- duration
// tracks 1/waves, so (256,3) was actually fitting 3 blocks/CU. Both occupancy
// directions from (256,3) measured dead ends; K-prefetch twice measured
// valueless. This structure's attn optimum = R4 = 139us. Reverted exactly.
__global__ __launch_bounds__(256, 3) void attn12_kernel(
    const unsigned short* __restrict__ Qh, const unsigned short* __restrict__ Ql,
    const unsigned short* __restrict__ Kh, const unsigned short* __restrict__ Kl,
    const unsigned short* __restrict__ Vt, const unsigned short* __restrict__ btPad,
    unsigned short* __restrict__ Oh, unsigned short* __restrict__ Ol)
{
  __shared__ __align__(16) unsigned short sPh[2][128 * 72];  // 36,864 B, rows wave-private

  int bid0 = blockIdx.x;
  int bid = (bid0 & 7) * 600 + (bid0 >> 3);   // 4800 % 8 == 0 -> bijective XCD swizzle
  int lt = bid % 3; int rest = bid / 3;
  int h = rest & 7; rest >>= 3;
  int v = rest % 25; int b = rest / 25;
  int l0 = lt * 128;
  int tid = threadIdx.x;
  int w = tid >> 6, lane = tid & 63, quad = lane >> 4, c16 = lane & 15;
  if (l0 + 32 * w >= TT) return;  // fully-garbage wave: no barriers, sPh wave-private
  size_t tbase = ((size_t)(b * VV + v) * HH + h) * TT;
  size_t vbase = ((size_t)(b * VV + v) * HH + h) * HD;

  bf16x8 qh[2], qlw[2];
  #pragma unroll
  for (int mt = 0; mt < 2; ++mt) {
    size_t qo = (tbase + l0 + w * 32 + mt * 16 + c16) * HD + quad * 8;
    qh[mt]  = *(const bf16x8*)&Qh[qo];
    qlw[mt] = *(const bf16x8*)&Ql[qo];
  }

  // rt-invariant bpermute addresses + selects (per reg)
  int srcaddr[4]; bool sel[4];
  #pragma unroll
  for (int reg = 0; reg < 4; ++reg) {
    srcaddr[reg] = 4 * (quad * 16 + ((15 + 4 * quad + reg - c16) & 15));
    sel[reg] = (4 * quad + reg) > c16;   // a==4
  }

  f32x4 accO[2][2];
  #pragma unroll
  for (int mt = 0; mt < 2; ++mt)
    #pragma unroll
    for (int no = 0; no < 2; ++no)
      accO[mt][no] = (f32x4){0.f, 0.f, 0.f, 0.f};
  float psum[2][4] = {{0.f, 0.f, 0.f, 0.f}, {0.f, 0.f, 0.f, 0.f}};

  #pragma unroll
  for (int rt = 0; rt < 5; ++rt) {
    const int r0 = rt * 64;
    unsigned short* myP = &sPh[rt & 1][32 * w * 72];

    // ---- K loads (shared by both row-tiles) + V (prev tile) + 6 distinct bt tiles ----
    const unsigned short* kb = &Kh[(tbase + r0 + c16) * HD + quad * 8];
    const unsigned short* lb = &Kl[(tbase + r0 + c16) * HD + quad * 8];
    bf16x8 khv[4], klv[4];
    #pragma unroll
    for (int nt = 0; nt < 4; ++nt) {
      khv[nt] = *(const bf16x8*)&kb[nt * 16 * HD];
      klv[nt] = *(const bf16x8*)&lb[nt * 16 * HD];
    }
    bf16x8 vv[2][2];
    if (rt > 0) {
      int p0 = r0 - 64;  // previous tile's base
      #pragma unroll
      for (int kc = 0; kc < 2; ++kc)
        #pragma unroll
        for (int no = 0; no < 2; ++no)
          vv[kc][no] = *(const bf16x8*)&Vt[(vbase + no * 16 + c16) * 320 + p0 + kc * 32 + quad * 8];
    }
    // bt6[j]: rows (l0+256+32w-r0) + 16j + c16; row-tile mt uses j = mt+n5, n5=0..4
    const unsigned short* btb = &btPad[(size_t)(l0 + 256 + 32 * w - r0 + c16) * HD + quad * 8];
    bf16x8 bt6[6];
    #pragma unroll
    for (int j = 0; j < 6; ++j) bt6[j] = *(const bf16x8*)&btb[j * 16 * HD];

    // ---- per row-tile: rolling per-nt pipeline ----
    #pragma unroll
    for (int mt = 0; mt < 2; ++mt) {
      float Bhi[4], Blo[4];
      {
        f32x4 r = {0.f, 0.f, 0.f, 0.f};
        r = __builtin_amdgcn_mfma_f32_16x16x32_bf16(qh[mt], bt6[mt + 4], r, 0, 0, 0);
        #pragma unroll
        for (int reg = 0; reg < 4; ++reg) Bhi[reg] = bperm(srcaddr[reg], r[reg]);
      }
      #pragma unroll
      for (int nt = 0; nt < 4; ++nt) {
        f32x4 sc = {0.f, 0.f, 0.f, 0.f};
        sc = __builtin_amdgcn_mfma_f32_16x16x32_bf16(qh[mt],  khv[nt], sc, 0, 0, 0);
        sc = __builtin_amdgcn_mfma_f32_16x16x32_bf16(qlw[mt], khv[nt], sc, 0, 0, 0);
        sc = __builtin_amdgcn_mfma_f32_16x16x32_bf16(qh[mt],  klv[nt], sc, 0, 0, 0);
        f32x4 r = {0.f, 0.f, 0.f, 0.f};
        r = __builtin_amdgcn_mfma_f32_16x16x32_bf16(qh[mt], bt6[mt + 3 - nt], r, 0, 0, 0);
        #pragma unroll
        for (int reg = 0; reg < 4; ++reg) Blo[reg] = bperm(srcaddr[reg], r[reg]);

        bool bad = (r0 + nt * 16 + c16) >= TT;
        #pragma unroll
        for (int reg = 0; reg < 4; ++reg) {
          float ri = sel[reg] ? Bhi[reg] : Blo[reg];
          float p = bad ? 0.f : __builtin_amdgcn_exp2f(sc[reg] + ri);
          psum[mt][reg] += p;
          myP[(mt * 16 + 4 * quad + reg) * 72 + nt * 16 + c16] = f2bf(p);
        }
        #pragma unroll
        for (int reg = 0; reg < 4; ++reg) Bhi[reg] = Blo[reg];
      }
    }

    // ---- PV for PREVIOUS tile (buffer (rt-1)&1) ----
    if (rt > 0) {
      unsigned short* prevP = &sPh[(rt - 1) & 1][32 * w * 72];
      #pragma unroll
      for (int mt = 0; mt < 2; ++mt)
        #pragma unroll
        for (int kc = 0; kc < 2; ++kc) {
          bf16x8 pf = *(const bf16x8*)&prevP[(mt * 16 + c16) * 72 + kc * 32 + quad * 8];
          #pragma unroll
          for (int no = 0; no < 2; ++no)
            accO[mt][no] = __builtin_amdgcn_mfma_f32_16x16x32_bf16(pf, vv[kc][no], accO[mt][no], 0, 0, 0);
        }
    }
  }
  // ---- tail PV for rt=4 (buffer 0) ----
  {
    int p0 = 4 * 64;
    unsigned short* prevP = &sPh[0][32 * w * 72];
    #pragma unroll
    for (int kc = 0; kc < 2; ++kc) {
      bf16x8 vfr[2];
      #pragma unroll
      for (int no = 0; no < 2; ++no)
        vfr[no] = *(const bf16x8*)&Vt[(vbase + no * 16 + c16) * 320 + p0 + kc * 32 + quad * 8];
      #pragma unroll
      for (int mt = 0; mt < 2; ++mt) {
        bf16x8 pf = *(const bf16x8*)&prevP[(mt * 16 + c16) * 72 + kc * 32 + quad * 8];
        #pragma unroll
        for (int no = 0; no < 2; ++no)
          accO[mt][no] = __builtin_amdgcn_mfma_f32_16x16x32_bf16(pf, vfr[no], accO[mt][no], 0, 0, 0);
      }
    }
  }

  // ---- row-sum reduce + epilogue ----
  #pragma unroll
  for (int mt = 0; mt < 2; ++mt)
    #pragma unroll
    for (int reg = 0; reg < 4; ++reg) {
      #pragma unroll
      for (int off = 1; off <= 8; off <<= 1)
        psum[mt][reg] += __shfl_xor(psum[mt][reg], off);
    }
  size_t obase = (size_t)(b * VV + v) * TT;
  #pragma unroll
  for (int mt = 0; mt < 2; ++mt)
    #pragma unroll
    for (int no = 0; no < 2; ++no)
      #pragma unroll
      for (int reg = 0; reg < 4; ++reg) {
        int gl = l0 + 32 * w + 16 * mt + 4 * quad + reg;
        if (gl < TT) {
          float o = accO[mt][no][reg] / psum[mt][reg];
          size_t oi = (obase + gl) * EE + h * HD + no * 16 + c16;
          unsigned short hb = f2bf(o);
          Oh[oi] = hb; Ol[oi] = f2bf(o - bf2f(hb));
        }
      }
}

// ---------------- Kernel C: merge projection, 2000 blocks (t-tiles of 30) ----------------
// (256,8) measured neutral in R1's accidental A/B -- keep (256,4).
__global__ __launch_bounds__(256, 4) void merge3_kernel(
    const unsigned short* __restrict__ Oh, const unsigned short* __restrict__ Ol,
    const unsigned short* __restrict__ WhT, const unsigned short* __restrict__ WlT,
    const float* __restrict__ b_merge, float* __restrict__ out)
{
  int blk = blockIdx.x;
  int tt = blk % 10; blk /= 10;
  int v = blk % 25; int b = blk / 25;
  int nb = b >> 1, mm = b & 1;
  int tid = threadIdx.x;
  int w = tid >> 6, lane = tid & 63, quad = lane >> 4, c16 = lane & 15;
  size_t obase = (size_t)(b * VV + v) * TT;
  int t0 = tt * 30;
  int cidx = w * 16 + c16;

  f32x4 acc[2];
  acc[0] = (f32x4){0.f, 0.f, 0.f, 0.f};
  acc[1] = (f32x4){0.f, 0.f, 0.f, 0.f};

  for (int ks = 0; ks < 8; ++ks) {
    int eoff = ks * 32 + quad * 8;
    bf16x8 bh = *(const bf16x8*)&WhT[(size_t)cidx * EE + eoff];
    bf16x8 bl = *(const bf16x8*)&WlT[(size_t)cidx * EE + eoff];
    bf16x8 ahv[2], alv[2];
    #pragma unroll
    for (int mt = 0; mt < 2; ++mt) {
      size_t ao = (obase + t0 + mt * 16 + c16) * EE + eoff;
      ahv[mt] = *(const bf16x8*)&Oh[ao];
      alv[mt] = *(const bf16x8*)&Ol[ao];
    }
    #pragma unroll
    for (int mt = 0; mt < 2; ++mt) {
      acc[mt] = __builtin_amdgcn_mfma_f32_16x16x32_bf16(ahv[mt], bh, acc[mt], 0, 0, 0);
      acc[mt] = __builtin_amdgcn_mfma_f32_16x16x32_bf16(alv[mt], bh, acc[mt], 0, 0, 0);
      acc[mt] = __builtin_amdgcn_mfma_f32_16x16x32_bf16(ahv[mt], bl, acc[mt], 0, 0, 0);
    }
  }
  float bm = b_merge[cidx];
  #pragma unroll
  for (int mt = 0; mt < 2; ++mt)
    #pragma unroll
    for (int reg = 0; reg < 4; ++reg) {
      int lrow = mt * 16 + 4 * quad + reg;
      if (lrow < 30) {
        int t = t0 + lrow;
        out[(((size_t)nb * CC + cidx) * VV + v) * TT * MM + (size_t)t * MM + mm]
            = acc[mt][reg] + bm;
      }
    }
}

extern "C" void kernel_launch(void* const* d_in, const int* in_sizes, int n_in,
                              void* d_out, int out_size, void* d_ws, size_t ws_size,
                              hipStream_t stream) {
  const float* x          = (const float*)d_in[0];
  const float* w_qkv      = (const float*)d_in[1];
  const float* b_qkv      = (const float*)d_in[2];
  const float* w_merge    = (const float*)d_in[3];
  const float* b_merge    = (const float*)d_in[4];
  const float* bias_table = (const float*)d_in[5];
  float* out = (float*)d_out;
  unsigned short* ws16 = (unsigned short*)d_ws;
  unsigned short* Qh   = ws16;
  unsigned short* Ql   = ws16 + (size_t)QKN;
  unsigned short* Kh   = ws16 + (size_t)2 * QKN;
  unsigned short* Kl   = ws16 + (size_t)3 * QKN;
  unsigned short* Vt   = ws16 + (size_t)4 * QKN;
  unsigned short* Oh   = ws16 + (size_t)4 * QKN + VTN;
  unsigned short* Ol   = ws16 + (size_t)5 * QKN + VTN;
  unsigned short* base8 = ws16 + (size_t)6 * QKN + VTN;
  unsigned short* WhT  = base8;
  unsigned short* WlT  = base8 + 16384;
  unsigned short* WqTh = base8 + 32768;
  unsigned short* WqTl = base8 + 81920;
  unsigned short* btPad = base8 + 131072;

  prep_kernel<<<dim3(344), dim3(256), 0, stream>>>(w_qkv, w_merge, bias_table,
                                                   WqTh, WqTl, WhT, WlT, btPad);
  qkv_kernel<<<dim3(1000), dim3(256), 0, stream>>>(x, b_qkv, WqTh, WqTl,
                                                   Qh, Ql, Kh, Kl, Vt);
  attn12_kernel<<<dim3(4800), dim3(256), 0, stream>>>(Qh, Ql, Kh, Kl, Vt, btPad, Oh, Ol);
  merge3_kernel<<<dim3(2000), dim3(256), 0, stream>>>(Oh, Ol, WhT, WlT, b_merge, out);
}

// Round 9
// 298.117 us; speedup vs baseline: 1.3210x; 1.0600x over previous
//
#include <hip/hip_runtime.h>
#include <cstdint>

#define NN 4
#define CC 64
#define VV 25
#define TT 300
#define MM 2
#define HH 8
#define HD 32
#define EE 256

typedef short bf16x8 __attribute__((ext_vector_type(8)));
typedef float f32x4 __attribute__((ext_vector_type(4)));
typedef float f32x2 __attribute__((ext_vector_type(2)));
typedef unsigned int u32x4 __attribute__((ext_vector_type(4)));

__device__ __forceinline__ unsigned short f2bf(float f) {
  union { float f; unsigned u; } x; x.f = f;
  unsigned r = x.u + 0x7FFF + ((x.u >> 16) & 1);  // RNE
  return (unsigned short)(r >> 16);
}
__device__ __forceinline__ float bf2f(unsigned short s) {
  union { unsigned u; float f; } x; x.u = ((unsigned)s) << 16;
  return x.f;
}
// truncation split: hi = upper 16 bits (1 op vs 4 for RNE). Pair precision
// unchanged: |lo| <= 2^-8|s| (vs 2^-9), lo's RNE error <= 2^-17|s| either way.
__device__ __forceinline__ unsigned short truncbf(float f) {
  union { float f; unsigned u; } x; x.f = f;
  return (unsigned short)(x.u >> 16);
}
__device__ __forceinline__ float bperm(int byteaddr, float v) {
  return __int_as_float(__builtin_amdgcn_ds_bpermute(byteaddr, __float_as_int(v)));
}

// ws layout (unsigned short units):
//   Qh,Ql,Kh,Kl : [b,v,h,t<300,d] (15,360,000 each) [Q xlog2e, K x1/16]
//   Vt : [b,v,h,d][t pad 320] (16,384,000)
//   Oh,Ol : [b,v,t<300,e] (15,360,000 each)
//   WhT,WlT [c][e] (16,384 each); WqTh,WqTl [e][c] (49,152 each);
//   btPad [704][32] bf16, rows 20..618 = bias_table, else 0 (22,528)
#define QKN 15360000
#define VTN 16384000
#define LOG2E 1.4426950408889634f

// ---------------- prep: transpose/split weights + bf16 bias table ----------------
__global__ __launch_bounds__(256) void prep_kernel(
    const float* __restrict__ w_qkv, const float* __restrict__ w_merge,
    const float* __restrict__ bias_table,
    unsigned short* __restrict__ WqTh, unsigned short* __restrict__ WqTl,
    unsigned short* __restrict__ WhT, unsigned short* __restrict__ WlT,
    unsigned short* __restrict__ btPad)
{
  int i = blockIdx.x * 256 + threadIdx.x;
  if (i < 49152) {                      // w_qkv [c][768] -> [e][c] hi/lo
    int c = i / 768, e = i % 768;
    float v = w_qkv[i];
    unsigned short hb = truncbf(v);
    WqTh[e * 64 + c] = hb; WqTl[e * 64 + c] = f2bf(v - bf2f(hb));
  } else if (i < 65536) {               // w_merge [e][64] -> [c][e] hi/lo
    int j = i - 49152;
    int e = j >> 6, c = j & 63;
    float v = w_merge[j];
    unsigned short hb = truncbf(v);
    WhT[c * EE + e] = hb; WlT[c * EE + e] = f2bf(v - bf2f(hb));
  } else if (i < 65536 + 22528) {       // bias_table -> padded bf16 [704][32]
    int j = i - 65536;
    int row = j >> 5, d = j & 31;
    int g = row - 20;
    float v = (g >= 0 && g < 2 * TT - 1) ? bias_table[g * 32 + d] : 0.f;
    btPad[j] = f2bf(v);
  }
}

// ---------------- Kernel A: QKV projection via MFMA ----------------
// R8: truncation hi-split in staging AND the Q/K store epilogue. The epilogue
// is qkv's VALU hog (~12 nt x 16 elems x ~12 ops/thread); trunc-split cuts
// the per-element split cost 10 -> 7 ops. Packed-LDS staging (R7) kept.
__global__ __launch_bounds__(256, 3) void qkv_kernel(
    const float* __restrict__ x, const float* __restrict__ b_qkv,
    const unsigned short* __restrict__ WqTh, const unsigned short* __restrict__ WqTl,
    unsigned short* __restrict__ Qh, unsigned short* __restrict__ Ql,
    unsigned short* __restrict__ Kh, unsigned short* __restrict__ Kl,
    unsigned short* __restrict__ Vt)
{
  __shared__ __align__(16) union {
    unsigned int a[64 * 68];      // sA2[t][c] packed (hi<<16)|lo, stride 68
    unsigned short vtr[256 * 66]; // V transpose buffer [e'][t]
  } sm;

  int blk = blockIdx.x;
  int tt = blk % 5; blk /= 5;
  int v25 = blk % 25; int b = blk / 25;
  int n = b >> 1, m = b & 1;
  int t0 = tt * 60;
  int tid = threadIdx.x;
  int w = tid >> 6, lane = tid & 63, quad = lane >> 4, c16 = lane & 15;

  for (int i = tid; i < 64 * 64; i += 256) {
    int c = i >> 6, t = i & 63;
    float val = 0.f;
    if (t < 60) val = x[((((size_t)n * CC + c) * VV + v25) * TT + (t0 + t)) * MM + m];
    union { float f; unsigned u; } xb; xb.f = val;
    unsigned hi16 = xb.u & 0xFFFF0000u;
    unsigned short lb = f2bf(val - __uint_as_float(hi16));
    sm.a[t * 68 + c] = hi16 | (unsigned)lb;
  }
  __syncthreads();

  bf16x8 ah[4][2], al[4][2];
  #pragma unroll
  for (int mt = 0; mt < 4; ++mt)
    #pragma unroll
    for (int kc = 0; kc < 2; ++kc) {
      const u32x4* p = (const u32x4*)&sm.a[(mt * 16 + c16) * 68 + kc * 32 + quad * 8];
      u32x4 u0 = p[0], u1 = p[1];
      unsigned e0 = u0[0], e1 = u0[1], e2 = u0[2], e3 = u0[3];
      unsigned e4 = u1[0], e5 = u1[1], e6 = u1[2], e7 = u1[3];
      union { unsigned u[4]; bf16x8 v; } H, L;
      H.u[0] = (e1 & 0xFFFF0000u) | (e0 >> 16);
      H.u[1] = (e3 & 0xFFFF0000u) | (e2 >> 16);
      H.u[2] = (e5 & 0xFFFF0000u) | (e4 >> 16);
      H.u[3] = (e7 & 0xFFFF0000u) | (e6 >> 16);
      L.u[0] = (e1 << 16) | (e0 & 0xFFFFu);
      L.u[1] = (e3 << 16) | (e2 & 0xFFFFu);
      L.u[2] = (e5 << 16) | (e4 & 0xFFFFu);
      L.u[3] = (e7 << 16) | (e6 & 0xFFFFu);
      ah[mt][kc] = H.v;
      al[mt][kc] = L.v;
    }
  __syncthreads();  // sA dead; sVt (union) may be written

  size_t bv = (size_t)(b * VV + v25);
  int e0w = w * 192;
  for (int nt = 0; nt < 12; ++nt) {
    int ebase = e0w + nt * 16;
    int e = ebase + c16;
    bf16x8 bh[2], bl[2];
    #pragma unroll
    for (int kc = 0; kc < 2; ++kc) {
      bh[kc] = *(const bf16x8*)&WqTh[(size_t)e * 64 + kc * 32 + quad * 8];
      bl[kc] = *(const bf16x8*)&WqTl[(size_t)e * 64 + kc * 32 + quad * 8];
    }
    f32x4 acc[4];
    #pragma unroll
    for (int mt = 0; mt < 4; ++mt) {
      acc[mt] = (f32x4){0.f, 0.f, 0.f, 0.f};
      #pragma unroll
      for (int kc = 0; kc < 2; ++kc) {
        acc[mt] = __builtin_amdgcn_mfma_f32_16x16x32_bf16(ah[mt][kc], bh[kc], acc[mt], 0, 0, 0);
        acc[mt] = __builtin_amdgcn_mfma_f32_16x16x32_bf16(al[mt][kc], bh[kc], acc[mt], 0, 0, 0);
        acc[mt] = __builtin_amdgcn_mfma_f32_16x16x32_bf16(ah[mt][kc], bl[kc], acc[mt], 0, 0, 0);
      }
    }
    float bias = b_qkv[e];
    int which = ebase >> 8;  // wave-uniform
    if (which < 2) {
      float sc = (which == 0) ? LOG2E : 0.0625f;
      unsigned short* Dh = (which == 0) ? Qh : Kh;
      unsigned short* Dl = (which == 0) ? Ql : Kl;
      int hh = (e >> 5) & 7, dd = e & 31;
      size_t rowb = (bv * HH + hh) * TT;
      #pragma unroll
      for (int mt = 0; mt < 4; ++mt)
        #pragma unroll
        for (int reg = 0; reg < 4; ++reg) {
          int lrow = mt * 16 + quad * 4 + reg;
          // rows >= 60 would RACE with the next tt-block (zero-staged x)
          if (lrow < 60) {
            int t = t0 + lrow;
            float s = (acc[mt][reg] + bias) * sc;
            unsigned short hb = truncbf(s);
            size_t idx = (rowb + t) * HD + dd;
            Dh[idx] = hb; Dl[idx] = f2bf(s - bf2f(hb));
          }
        }
    } else {
      int ep = e - 512;
      #pragma unroll
      for (int mt = 0; mt < 4; ++mt)
        #pragma unroll
        for (int reg = 0; reg < 4; ++reg)
          sm.vtr[ep * 66 + mt * 16 + quad * 4 + reg] = f2bf(acc[mt][reg] + bias);
    }
  }
  __syncthreads();
  for (int i = tid; i < 256 * 30; i += 256) {
    int ep = i / 30, tc = (i % 30) * 2;
    int e = 512 + ep;
    int hh = (e >> 5) & 7, dd = e & 31;
    size_t idx = ((bv * HH + hh) * HD + dd) * 320 + t0 + tc;
    *(unsigned int*)&Vt[idx] = *(const unsigned int*)&sm.vtr[ep * 66 + tc];
    // Vt rows t in [300,320) stay poison (finite bf16) -> always hit P=0.
  }
}

// ---------------- Kernel B: MFMA attention, 32 rows/wave (R4 structure) ----------------
// R4 = this structure's optimum (139-145us). Only change in R8: trunc-split in
// the O epilogue (provable same pair precision).
__global__ __launch_bounds__(256, 3) void attn12_kernel(
    const unsigned short* __restrict__ Qh, const unsigned short* __restrict__ Ql,
    const unsigned short* __restrict__ Kh, const unsigned short* __restrict__ Kl,
    const unsigned short* __restrict__ Vt, const unsigned short* __restrict__ btPad,
    unsigned short* __restrict__ Oh, unsigned short* __restrict__ Ol)
{
  __shared__ __align__(16) unsigned short sPh[2][128 * 72];  // 36,864 B, rows wave-private

  int bid0 = blockIdx.x;
  int bid = (bid0 & 7) * 600 + (bid0 >> 3);   // 4800 % 8 == 0 -> bijective XCD swizzle
  int lt = bid % 3; int rest = bid / 3;
  int h = rest & 7; rest >>= 3;
  int v = rest % 25; int b = rest / 25;
  int l0 = lt * 128;
  int tid = threadIdx.x;
  int w = tid >> 6, lane = tid & 63, quad = lane >> 4, c16 = lane & 15;
  if (l0 + 32 * w >= TT) return;  // fully-garbage wave: no barriers, sPh wave-private
  size_t tbase = ((size_t)(b * VV + v) * HH + h) * TT;
  size_t vbase = ((size_t)(b * VV + v) * HH + h) * HD;

  bf16x8 qh[2], qlw[2];
  #pragma unroll
  for (int mt = 0; mt < 2; ++mt) {
    size_t qo = (tbase + l0 + w * 32 + mt * 16 + c16) * HD + quad * 8;
    qh[mt]  = *(const bf16x8*)&Qh[qo];
    qlw[mt] = *(const bf16x8*)&Ql[qo];
  }

  // rt-invariant bpermute addresses + selects (per reg)
  int srcaddr[4]; bool sel[4];
  #pragma unroll
  for (int reg = 0; reg < 4; ++reg) {
    srcaddr[reg] = 4 * (quad * 16 + ((15 + 4 * quad + reg - c16) & 15));
    sel[reg] = (4 * quad + reg) > c16;   // a==4
  }

  f32x4 accO[2][2];
  #pragma unroll
  for (int mt = 0; mt < 2; ++mt)
    #pragma unroll
    for (int no = 0; no < 2; ++no)
      accO[mt][no] = (f32x4){0.f, 0.f, 0.f, 0.f};
  float psum[2][4] = {{0.f, 0.f, 0.f, 0.f}, {0.f, 0.f, 0.f, 0.f}};

  #pragma unroll
  for (int rt = 0; rt < 5; ++rt) {
    const int r0 = rt * 64;
    unsigned short* myP = &sPh[rt & 1][32 * w * 72];

    // ---- K loads (shared by both row-tiles) + V (prev tile) + 6 distinct bt tiles ----
    const unsigned short* kb = &Kh[(tbase + r0 + c16) * HD + quad * 8];
    const unsigned short* lb = &Kl[(tbase + r0 + c16) * HD + quad * 8];
    bf16x8 khv[4], klv[4];
    #pragma unroll
    for (int nt = 0; nt < 4; ++nt) {
      khv[nt] = *(const bf16x8*)&kb[nt * 16 * HD];
      klv[nt] = *(const bf16x8*)&lb[nt * 16 * HD];
    }
    bf16x8 vv[2][2];
    if (rt > 0) {
      int p0 = r0 - 64;  // previous tile's base
      #pragma unroll
      for (int kc = 0; kc < 2; ++kc)
        #pragma unroll
        for (int no = 0; no < 2; ++no)
          vv[kc][no] = *(const bf16x8*)&Vt[(vbase + no * 16 + c16) * 320 + p0 + kc * 32 + quad * 8];
    }
    // bt6[j]: rows (l0+256+32w-r0) + 16j + c16; row-tile mt uses j = mt+n5, n5=0..4
    const unsigned short* btb = &btPad[(size_t)(l0 + 256 + 32 * w - r0 + c16) * HD + quad * 8];
    bf16x8 bt6[6];
    #pragma unroll
    for (int j = 0; j < 6; ++j) bt6[j] = *(const bf16x8*)&btb[j * 16 * HD];

    // ---- per row-tile: rolling per-nt pipeline ----
    #pragma unroll
    for (int mt = 0; mt < 2; ++mt) {
      float Bhi[4], Blo[4];
      {
        f32x4 r = {0.f, 0.f, 0.f, 0.f};
        r = __builtin_amdgcn_mfma_f32_16x16x32_bf16(qh[mt], bt6[mt + 4], r, 0, 0, 0);
        #pragma unroll
        for (int reg = 0; reg < 4; ++reg) Bhi[reg] = bperm(srcaddr[reg], r[reg]);
      }
      #pragma unroll
      for (int nt = 0; nt < 4; ++nt) {
        f32x4 sc = {0.f, 0.f, 0.f, 0.f};
        sc = __builtin_amdgcn_mfma_f32_16x16x32_bf16(qh[mt],  khv[nt], sc, 0, 0, 0);
        sc = __builtin_amdgcn_mfma_f32_16x16x32_bf16(qlw[mt], khv[nt], sc, 0, 0, 0);
        sc = __builtin_amdgcn_mfma_f32_16x16x32_bf16(qh[mt],  klv[nt], sc, 0, 0, 0);
        f32x4 r = {0.f, 0.f, 0.f, 0.f};
        r = __builtin_amdgcn_mfma_f32_16x16x32_bf16(qh[mt], bt6[mt + 3 - nt], r, 0, 0, 0);
        #pragma unroll
        for (int reg = 0; reg < 4; ++reg) Blo[reg] = bperm(srcaddr[reg], r[reg]);

        bool bad = (r0 + nt * 16 + c16) >= TT;
        #pragma unroll
        for (int reg = 0; reg < 4; ++reg) {
          float ri = sel[reg] ? Bhi[reg] : Blo[reg];
          float p = bad ? 0.f : __builtin_amdgcn_exp2f(sc[reg] + ri);
          psum[mt][reg] += p;
          myP[(mt * 16 + 4 * quad + reg) * 72 + nt * 16 + c16] = f2bf(p);
        }
        #pragma unroll
        for (int reg = 0; reg < 4; ++reg) Bhi[reg] = Blo[reg];
      }
    }

    // ---- PV for PREVIOUS tile (buffer (rt-1)&1) ----
    if (rt > 0) {
      unsigned short* prevP = &sPh[(rt - 1) & 1][32 * w * 72];
      #pragma unroll
      for (int mt = 0; mt < 2; ++mt)
        #pragma unroll
        for (int kc = 0; kc < 2; ++kc) {
          bf16x8 pf = *(const bf16x8*)&prevP[(mt * 16 + c16) * 72 + kc * 32 + quad * 8];
          #pragma unroll
          for (int no = 0; no < 2; ++no)
            accO[mt][no] = __builtin_amdgcn_mfma_f32_16x16x32_bf16(pf, vv[kc][no], accO[mt][no], 0, 0, 0);
        }
    }
  }
  // ---- tail PV for rt=4 (buffer 0) ----
  {
    int p0 = 4 * 64;
    unsigned short* prevP = &sPh[0][32 * w * 72];
    #pragma unroll
    for (int kc = 0; kc < 2; ++kc) {
      bf16x8 vfr[2];
      #pragma unroll
      for (int no = 0; no < 2; ++no)
        vfr[no] = *(const bf16x8*)&Vt[(vbase + no * 16 + c16) * 320 + p0 + kc * 32 + quad * 8];
      #pragma unroll
      for (int mt = 0; mt < 2; ++mt) {
        bf16x8 pf = *(const bf16x8*)&prevP[(mt * 16 + c16) * 72 + kc * 32 + quad * 8];
        #pragma unroll
        for (int no = 0; no < 2; ++no)
          accO[mt][no] = __builtin_amdgcn_mfma_f32_16x16x32_bf16(pf, vfr[no], accO[mt][no], 0, 0, 0);
      }
    }
  }

  // ---- row-sum reduce + epilogue ----
  #pragma unroll
  for (int mt = 0; mt < 2; ++mt)
    #pragma unroll
    for (int reg = 0; reg < 4; ++reg) {
      #pragma unroll
      for (int off = 1; off <= 8; off <<= 1)
        psum[mt][reg] += __shfl_xor(psum[mt][reg], off);
    }
  size_t obase = (size_t)(b * VV + v) * TT;
  #pragma unroll
  for (int mt = 0; mt < 2; ++mt)
    #pragma unroll
    for (int no = 0; no < 2; ++no)
      #pragma unroll
      for (int reg = 0; reg < 4; ++reg) {
        int gl = l0 + 32 * w + 16 * mt + 4 * quad + reg;
        if (gl < TT) {
          float o = accO[mt][no][reg] / psum[mt][reg];
          size_t oi = (obase + gl) * EE + h * HD + no * 16 + c16;
          unsigned short hb = truncbf(o);
          Oh[oi] = hb; Ol[oi] = f2bf(o - bf2f(hb));
        }
      }
}

// ---------------- Kernel C: merge projection, m-fused, 1000 blocks ----------------
// R8: fuse the m-pair into one block. Out layout [n][c][v][t][m] has m
// innermost: with both m accumulated per block, the store becomes a
// contiguous float2 (t,m0),(t,m1) at 8B -- halves transactions on a store
// pattern whose lanes scatter across c (60KB stride, every store its own
// transaction). W-tile reads also halve (shared across the m-pair).
__global__ __launch_bounds__(256, 4) void merge4_kernel(
    const unsigned short* __restrict__ Oh, const unsigned short* __restrict__ Ol,
    const unsigned short* __restrict__ WhT, const unsigned short* __restrict__ WlT,
    const float* __restrict__ b_merge, float* __restrict__ out)
{
  int blk = blockIdx.x;
  int tt = blk % 10; blk /= 10;
  int v = blk % 25; int nb = blk / 25;   // nb in [0,4)
  int tid = threadIdx.x;
  int w = tid >> 6, lane = tid & 63, quad = lane >> 4, c16 = lane & 15;
  int t0 = tt * 30;
  int cidx = w * 16 + c16;
  size_t obase0 = ((size_t)(nb * 2 + 0) * VV + v) * TT;
  size_t obase1 = ((size_t)(nb * 2 + 1) * VV + v) * TT;

  f32x4 acc[2][2];  // [mm][mt]
  #pragma unroll
  for (int mm = 0; mm < 2; ++mm)
    #pragma unroll
    for (int mt = 0; mt < 2; ++mt)
      acc[mm][mt] = (f32x4){0.f, 0.f, 0.f, 0.f};

  for (int ks = 0; ks < 8; ++ks) {
    int eoff = ks * 32 + quad * 8;
    bf16x8 bh = *(const bf16x8*)&WhT[(size_t)cidx * EE + eoff];
    bf16x8 bl = *(const bf16x8*)&WlT[(size_t)cidx * EE + eoff];
    #pragma unroll
    for (int mm = 0; mm < 2; ++mm) {
      size_t ob = (mm == 0) ? obase0 : obase1;
      #pragma unroll
      for (int mt = 0; mt < 2; ++mt) {
        size_t ao = (ob + t0 + mt * 16 + c16) * EE + eoff;
        bf16x8 ahv = *(const bf16x8*)&Oh[ao];
        bf16x8 alv = *(const bf16x8*)&Ol[ao];
        acc[mm][mt] = __builtin_amdgcn_mfma_f32_16x16x32_bf16(ahv, bh, acc[mm][mt], 0, 0, 0);
        acc[mm][mt] = __builtin_amdgcn_mfma_f32_16x16x32_bf16(alv, bh, acc[mm][mt], 0, 0, 0);
        acc[mm][mt] = __builtin_amdgcn_mfma_f32_16x16x32_bf16(ahv, bl, acc[mm][mt], 0, 0, 0);
      }
    }
  }
  float bm = b_merge[cidx];
  size_t rowbase = ((size_t)nb * CC + cidx) * VV + v;  // out row for (nb, cidx, v)
  #pragma unroll
  for (int mt = 0; mt < 2; ++mt)
    #pragma unroll
    for (int reg = 0; reg < 4; ++reg) {
      int lrow = mt * 16 + 4 * quad + reg;
      if (lrow < 30) {
        int t = t0 + lrow;
        f32x2 pr;
        pr[0] = acc[0][mt][reg] + bm;
        pr[1] = acc[1][mt][reg] + bm;
        *(f32x2*)&out[rowbase * TT * MM + (size_t)t * MM] = pr;
      }
    }
}

extern "C" void kernel_launch(void* const* d_in, const int* in_sizes, int n_in,
                              void* d_out, int out_size, void* d_ws, size_t ws_size,
                              hipStream_t stream) {
  const float* x          = (const float*)d_in[0];
  const float* w_qkv      = (const float*)d_in[1];
  const float* b_qkv      = (const float*)d_in[2];
  const float* w_merge    = (const float*)d_in[3];
  const float* b_merge    = (const float*)d_in[4];
  const float* bias_table = (const float*)d_in[5];
  float* out = (float*)d_out;
  unsigned short* ws16 = (unsigned short*)d_ws;
  unsigned short* Qh   = ws16;
  unsigned short* Ql   = ws16 + (size_t)QKN;
  unsigned short* Kh   = ws16 + (size_t)2 * QKN;
  unsigned short* Kl   = ws16 + (size_t)3 * QKN;
  unsigned short* Vt   = ws16 + (size_t)4 * QKN;
  unsigned short* Oh   = ws16 + (size_t)4 * QKN + VTN;
  unsigned short* Ol   = ws16 + (size_t)5 * QKN + VTN;
  unsigned short* base8 = ws16 + (size_t)6 * QKN + VTN;
  unsigned short* WhT  = base8;
  unsigned short* WlT  = base8 + 16384;
  unsigned short* WqTh = base8 + 32768;
  unsigned short* WqTl = base8 + 81920;
  unsigned short* btPad = base8 + 131072;

  prep_kernel<<<dim3(344), dim3(256), 0, stream>>>(w_qkv, w_merge, bias_table,
                                                   WqTh, WqTl, WhT, WlT, btPad);
  qkv_kernel<<<dim3(1000), dim3(256), 0, stream>>>(x, b_qkv, WqTh, WqTl,
                                                   Qh, Ql, Kh, Kl, Vt);
  attn12_kernel<<<dim3(4800), dim3(256), 0, stream>>>(Qh, Ql, Kh, Kl, Vt, btPad, Oh, Ol);
  merge4_kernel<<<dim3(1000), dim3(256), 0, stream>>>(Oh, Ol, WhT, WlT, b_merge, out);
}